// Round 12
// baseline (288.594 us; speedup 1.0000x reference)
//
#include <hip/hip_runtime.h>
#include <hip/hip_bf16.h>
#include <cstddef>
#include <cstdint>

// (B,T,I,H,K) = (32,1024,512,512,2)
#define B_  32
#define T_  1024
#define I_  512
#define H_  512
#define M_  (B_ * T_)     // 32768
#define TP_ 1025          // padded T rows (row 0 = zeros) per batch

typedef __bf16 bf16x8  __attribute__((ext_vector_type(8)));
typedef float  floatx4 __attribute__((ext_vector_type(4)));
typedef unsigned short ushort8v __attribute__((ext_vector_type(8)));
typedef unsigned long long u64;

__device__ __forceinline__ unsigned short f2bf(float f) {
    uint32_t u = __float_as_uint(f);
    return (unsigned short)((u + 0x7FFFu + ((u >> 16) & 1u)) >> 16);
}
__device__ __forceinline__ float sigm(float x) {
    return __builtin_amdgcn_rcpf(1.f + __expf(-x));
}

// ---------------------------------------------------------------------------
// Prep (unchanged).
//  Part 1: Ab2[b][trow][i] bf16 (trow 0 = zeros, else x[b][trow-1]).
//  Part 2: fragment-ordered weight pack
//    Wq[gate(2)][ni(4)][ksub(32)][wn(2)][c(4)][lane(64)][8] bf16.
//  Part 3: zero Hpub (1 MB) + 256 per-chain ticket counters.
// ---------------------------------------------------------------------------
#define NB_BUILD 8200    // 32*1025*512 / 8 / 256
#define NB_PACK  512     // 1,048,576 elems / 8 / 256
#define NB_ZERO  256     // 1 MB / 16 B / 256

__global__ __launch_bounds__(256) void prep(const float* __restrict__ x,
                                            const float* __restrict__ Wf,
                                            const float* __restrict__ Wz,
                                            unsigned short* __restrict__ Ab2,
                                            unsigned short* __restrict__ Wq,
                                            uint4* __restrict__ HpubZ,
                                            uint32_t* __restrict__ tickets) {
    if (blockIdx.x < NB_BUILD) {
        int g = blockIdx.x * 256 + threadIdx.x;     // 2,099,200
        int idx8 = g << 3;
        int row = idx8 >> 9;                        // 0 .. 32*1025-1
        int col = idx8 & 511;
        int b    = (int)((unsigned)row / TP_);
        int trow = row - b * TP_;
        ushort8v o = {0, 0, 0, 0, 0, 0, 0, 0};
        if (trow > 0) {
            const float* src = &x[((size_t)b * T_ + (trow - 1)) * I_ + col];
            float4 v0 = *(const float4*)src;
            float4 v1 = *(const float4*)(src + 4);
            o[0] = f2bf(v0.x); o[1] = f2bf(v0.y); o[2] = f2bf(v0.z); o[3] = f2bf(v0.w);
            o[4] = f2bf(v1.x); o[5] = f2bf(v1.y); o[6] = f2bf(v1.z); o[7] = f2bf(v1.w);
        }
        *(ushort8v*)&Ab2[(size_t)idx8] = o;
    } else if (blockIdx.x < NB_BUILD + NB_PACK) {
        int cid = (blockIdx.x - NB_BUILD) * 256 + threadIdx.x;  // 0..131071
        int lane = cid & 63;
        int c    = (cid >> 6) & 3;
        int wn   = (cid >> 8) & 1;
        int ksub = (cid >> 9) & 31;
        int ni   = (cid >> 14) & 3;
        int gate = (cid >> 16) & 1;
        int n_col = ni * 128 + wn * 64 + c * 16 + (lane & 15);
        const float* G = gate ? Wz : Wf;
        ushort8v o;
        #pragma unroll
        for (int j = 0; j < 8; ++j) {
            int k   = ksub * 32 + (lane >> 4) * 8 + j;
            int tap = k >> 9;
            int i   = k & 511;
            o[j] = f2bf(G[n_col * (I_ * 2) + i * 2 + tap]);
        }
        *(ushort8v*)&Wq[(size_t)cid * 8] = o;
    } else {
        int g = (blockIdx.x - NB_BUILD - NB_PACK) * 256 + threadIdx.x; // 0..65535
        HpubZ[g] = make_uint4(0, 0, 0, 0);
        if (g < 256) tickets[g] = 0;
    }
}

// ---------------------------------------------------------------------------
// Fused dual-gate MFMA GEMM + full scan via decoupled lookback.
//
// Round-11 post-mortem: occupancy 19->27.6%, FETCH ideal, yet dur 85->100us
// and MfmaUtil 34->28.8. MFMA-busy = ~28-29us = the 68.7 GFLOP floor in
// EVERY variant; the rest is per-K-step lockstep cost (vmcnt+s_barrier+
// 4-wave skew, 32x/block) which halving the per-step MFMA made relatively
// worse. The barrier exists only because waves read A-rows staged by other
// waves.
//
// THIS ROUND: BARRIER-FREE K-loop. A-fragments straight global->VGPR:
// verified identity  LDS_frag == Ab2[(browBase+tap+ml)*512 + i0 + quad*8],
// and tap*512+(ksub&15)*32 == ksub*32 (linear). B already reg-loaded.
// Both double-buffered one step ahead; compiler inserts counted vmcnt on
// the dependency; sched_barrier(0) pins load-issue above each MFMA
// cluster (prefetch order preserved). No LDS / GLL / s_barrier / lockstep
// in the loop -- waves drift freely, 3 waves/SIMD hide L2 latency.
// A read-amplification 2x (wh pair) is L2-only; 8 same-XCD nh-sharers.
// Geometry/decode/tickets/epilogue = R11 (passed). Regs ~150 -> (256,3)
// holds. Per-output math order unchanged => bitwise-identical results.
// ---------------------------------------------------------------------------
__global__ __launch_bounds__(256, 3) void mfma_gemm_scan(
        const unsigned short* __restrict__ Ab2,  // [32][1025][512]
        const unsigned short* __restrict__ Wq,   // fragment-ordered, 2 MB
        const float* __restrict__ biasF,
        const float* __restrict__ biasZ,
        float* __restrict__ out,                 // [M_][512] fp32
        u64* __restrict__ Hpub,                  // [8][256][64]
        uint32_t* __restrict__ tickets) {        // 256 chain counters
    // LDS: epilogue only. seg = float2[32][64] at [0,16KB); hinL at [16,24KB)
    __shared__ unsigned short smem[12288];       // 24 KB
    __shared__ uint32_t pos_s;

    const int tid = threadIdx.x;
    const int bid = blockIdx.x;
    const int x   = bid & 7;                     // XCD id (HW round-robin)
    const int nh  = (bid >> 3) & 7;              // h-block of 64
    const int q   = bid >> 6;                    // 0..31
    const int b   = ((q & 3) << 3) | x;          // 0..31
    const int chain = nh * 32 + b;               // 0..255
    if (tid == 0) pos_s = atomicAdd(&tickets[chain], 1u);
    __syncthreads();
    const int pos = (int)pos_s;                  // 0..7 = start rank in chain
    const int h0  = nh * 64;
    const int browBase = b * TP_ + pos * 128;    // Ab2 row of tile, tap0

    const int lane = tid & 63;
    const int wave = tid >> 6;
    const int wm   = wave >> 1;                  // t-half (64 rows)
    const int wh   = wave & 1;                   // h-half (32 cols)
    const int lm   = lane & 15, quad = lane >> 4;

    // A direct global->VGPR: frag r, lane(lm,quad), ksub:
    //   Ab2[(browBase + (ksub>>4) + wm*64 + r*16 + lm)*512 + (ksub&15)*32
    //       + quad*8]  ==  pA_base + r*8192 + ksub*32   (shorts)
    const unsigned short* pA_base =
        Ab2 + (size_t)(browBase + wm * 64 + lm) * 512 + quad * 8;

    // B direct global->VGPR (L2-hot), same mapping as R11:
    const unsigned short* pBF = Wq + (size_t)(nh >> 1) * 131072
                                   + (nh & 1) * 2048 + wh * 1024 + lane * 8;

    floatx4 accF[4][2] = {};
    floatx4 accZ[4][2] = {};
    bf16x8 aA[4], aB[4], bfA[2], bzA[2], bfB[2], bzB[2];

#define LOADA(ksub, AF) do {                                            \
        const unsigned short* pa_ = pA_base + (ksub) * 32;              \
        AF[0] = *(const bf16x8*)(pa_);                                  \
        AF[1] = *(const bf16x8*)(pa_ + 8192);                           \
        AF[2] = *(const bf16x8*)(pa_ + 16384);                          \
        AF[3] = *(const bf16x8*)(pa_ + 24576);                          \
    } while (0)

#define LOADB(ksub, BF, BZ) do {                                        \
        const unsigned short* pf_ = pBF + (ksub) * 4096;                \
        BF[0] = *(const bf16x8*)(pf_);                                  \
        BF[1] = *(const bf16x8*)(pf_ + 512);                            \
        BZ[0] = *(const bf16x8*)(pf_ + 524288);                         \
        BZ[1] = *(const bf16x8*)(pf_ + 524288 + 512);                   \
    } while (0)

#define MFMA16(AF, BF, BZ) do {                                         \
        __builtin_amdgcn_s_setprio(1);                                  \
        _Pragma("unroll")                                               \
        for (int r = 0; r < 4; ++r) {                                   \
            _Pragma("unroll")                                           \
            for (int c = 0; c < 2; ++c) {                               \
                accF[r][c] = __builtin_amdgcn_mfma_f32_16x16x32_bf16(   \
                                AF[r], BF[c], accF[r][c], 0, 0, 0);     \
                accZ[r][c] = __builtin_amdgcn_mfma_f32_16x16x32_bf16(   \
                                AF[r], BZ[c], accZ[r][c], 0, 0, 0);     \
            }                                                           \
        }                                                               \
        __builtin_amdgcn_s_setprio(0);                                  \
    } while (0)

    // prologue: ksub 0 -> buffer A
    LOADA(0, aA);
    LOADB(0, bfA, bzA);

    #pragma unroll 1
    for (int p = 0; p < 15; ++p) {
        const int k = 2 * p;
        LOADA(k + 1, aB);                 // prefetch next step (buffer B)
        LOADB(k + 1, bfB, bzB);
        __builtin_amdgcn_sched_barrier(0);
        MFMA16(aA, bfA, bzA);             // compute ksub k (waits its loads)
        __builtin_amdgcn_sched_barrier(0);
        LOADA(k + 2, aA);                 // prefetch k+2 (buffer A reuse)
        LOADB(k + 2, bfA, bzA);
        __builtin_amdgcn_sched_barrier(0);
        MFMA16(aB, bfB, bzB);             // compute ksub k+1
        __builtin_amdgcn_sched_barrier(0);
    }
    // aA holds ksub 30 (loaded in p=14)
    LOADA(31, aB);
    LOADB(31, bfB, bzB);
    __builtin_amdgcn_sched_barrier(0);
    MFMA16(aA, bfA, bzA);                 // ksub 30
    __builtin_amdgcn_sched_barrier(0);
    MFMA16(aB, bfB, bzB);                 // ksub 31
#undef LOADA
#undef LOADB
#undef MFMA16

    // ================= epilogue: sigmoid + segment affines =================
    float bfv[2], bzv[2];
    #pragma unroll
    for (int c = 0; c < 2; ++c) {
        int hc = h0 + wh * 32 + c * 16 + lm;
        bfv[c] = biasF[hc];
        bzv[c] = biasZ[hc];
    }

    float2* seg  = (float2*)smem;                // [32][64] 16 KB
    float*  hinL = (float*)&smem[8192];          // [32][64] 8 KB

    #pragma unroll
    for (int r = 0; r < 4; ++r) {
        const int sid = wm * 16 + r * 4 + quad;  // segment of 4 t's
        #pragma unroll
        for (int c = 0; c < 2; ++c) {
            float A = 1.f, C = 0.f;
            #pragma unroll
            for (int v = 0; v < 4; ++v) {
                float f = sigm(accF[r][c][v] + bfv[c]);
                float z = sigm(accZ[r][c][v] + bzv[c]);
                accF[r][c][v] = f;               // keep f
                accZ[r][c][v] = z;               // keep z
                A *= f;
                C = fmaf(f, C - z, z);
            }
            seg[sid * 64 + wh * 32 + c * 16 + lm] = make_float2(A, C);
        }
    }
    __syncthreads();

    // per-h block affine (threads 0..63), lookback, publish, entry states
    if (tid < 64) {
        const int h = tid;
        float At = 1.f, Ct = 0.f;
        #pragma unroll 8
        for (int s = 0; s < 32; ++s) {
            float2 sc = seg[s * 64 + h];
            Ct = fmaf(sc.x, Ct, sc.y);
            At *= sc.x;
        }
        float Hin = 0.f;
        if (pos > 0) {
            u64* p = &Hpub[((size_t)(pos - 1) * 256 + chain) * 64 + h];
            u64 v;
            while (((v = atomicAdd(p, 0ull)) >> 32) == 0ull)
                __builtin_amdgcn_s_sleep(2);
            Hin = __uint_as_float((uint32_t)v);
        }
        if (pos < 7) {
            float Hout = fmaf(At, Hin, Ct);
            u64 pv = 0x100000000ull | (u64)__float_as_uint(Hout);
            atomicExch(&Hpub[((size_t)pos * 256 + chain) * 64 + h], pv);
        }
        // per-segment entry states
        float run = Hin;
        #pragma unroll 8
        for (int s = 0; s < 32; ++s) {
            hinL[s * 64 + h] = run;
            float2 sc = seg[s * 64 + h];
            run = fmaf(sc.x, run, sc.y);
        }
    }
    __syncthreads();

    // replay tile from registers, write output
    const int rowBase = b * T_ + pos * 128;
    #pragma unroll
    for (int r = 0; r < 4; ++r) {
        const int sid = wm * 16 + r * 4 + quad;
        #pragma unroll
        for (int c = 0; c < 2; ++c) {
            const int hcl = wh * 32 + c * 16 + lm;   // local h 0..63
            float hs = hinL[sid * 64 + hcl];
            #pragma unroll
            for (int v = 0; v < 4; ++v) {
                float f = accF[r][c][v];
                float z = accZ[r][c][v];
                hs = fmaf(f, hs - z, z);
                const size_t row = (size_t)(rowBase + wm * 64 + r * 16 + quad * 4 + v);
                out[row * H_ + h0 + hcl] = hs;
            }
        }
    }
}

// ---------------------------------------------------------------------------
extern "C" void kernel_launch(void* const* d_in, const int* in_sizes, int n_in,
                              void* d_out, int out_size, void* d_ws, size_t ws_size,
                              hipStream_t stream) {
    const float* x  = (const float*)d_in[0];
    const float* Wz = (const float*)d_in[2];
    const float* bz = (const float*)d_in[3];
    const float* Wf = (const float*)d_in[4];
    const float* bf = (const float*)d_in[5];
    float* out = (float*)d_out;

    char* ws = (char*)d_ws;
    unsigned short* Ab2  = (unsigned short*)(ws);                            // 33.6 MB
    unsigned short* Wq   = (unsigned short*)(ws + (size_t)34 * 1024 * 1024); // 2 MB
    u64*            Hpub = (u64*)(ws + (size_t)36 * 1024 * 1024);            // 1 MB
    uint32_t*       tkt  = (uint32_t*)(ws + (size_t)37 * 1024 * 1024);       // 1 KB

    prep<<<NB_BUILD + NB_PACK + NB_ZERO, 256, 0, stream>>>(
        x, Wf, Wz, Ab2, Wq, (uint4*)Hpub, tkt);

    mfma_gemm_scan<<<2048, 256, 0, stream>>>(Ab2, Wq, bf, bz, out, Hpub, tkt);
}

// Round 13
// 191.820 us; speedup vs baseline: 1.5045x; 1.5045x over previous
//
#include <hip/hip_runtime.h>
#include <hip/hip_bf16.h>
#include <cstddef>
#include <cstdint>

// (B,T,I,H,K) = (32,1024,512,512,2)
#define B_  32
#define T_  1024
#define I_  512
#define H_  512
#define M_  (B_ * T_)     // 32768
#define TP_ 1025          // padded T rows (row 0 = zeros) per batch

typedef __bf16 bf16x8  __attribute__((ext_vector_type(8)));
typedef float  floatx4 __attribute__((ext_vector_type(4)));
typedef unsigned short ushort8v __attribute__((ext_vector_type(8)));
typedef unsigned long long u64;

// Native HW bf16 conversion (v_cvt_pk_bf16_f32, RTNE — bit-identical to the
// old manual round-nearest-even bit-twiddle, ~6 VALU/elem -> ~0.5).
// Round-12 post-mortem: prep was VALU-bound on the manual f2bf (~40-60us of
// the constant ~107us non-gemm time); m240: let the compiler emit cvt.
__device__ __forceinline__ unsigned short f2bf(float f) {
    return __builtin_bit_cast(unsigned short, (__bf16)f);
}
__device__ __forceinline__ float sigm(float x) {
    return __builtin_amdgcn_rcpf(1.f + __expf(-x));
}

#define GLL(src, dst) __builtin_amdgcn_global_load_lds( \
    (const __attribute__((address_space(1))) void*)(src), \
    (__attribute__((address_space(3))) void*)(dst), 16, 0, 0)

// ---------------------------------------------------------------------------
// Prep.
//  Part 1: Ab2[b][trow][i] bf16 (trow 0 = zeros, else x[b][trow-1]).
//  Part 2: fragment-ordered weight pack
//    Wq[gate(2)][ni(4)][ksub(32)][wn(2)][c(4)][lane(64)][8] bf16.
//  Part 3: zero Hpub (1 MB) + 128 per-chain ticket counters.
// ---------------------------------------------------------------------------
#define NB_BUILD 8200    // 32*1025*512 / 8 / 256
#define NB_PACK  512     // 1,048,576 elems / 8 / 256
#define NB_ZERO  256     // 1 MB / 16 B / 256

__global__ __launch_bounds__(256) void prep(const float* __restrict__ x,
                                            const float* __restrict__ Wf,
                                            const float* __restrict__ Wz,
                                            unsigned short* __restrict__ Ab2,
                                            unsigned short* __restrict__ Wq,
                                            uint4* __restrict__ HpubZ,
                                            uint32_t* __restrict__ tickets) {
    if (blockIdx.x < NB_BUILD) {
        int g = blockIdx.x * 256 + threadIdx.x;     // 2,099,200
        int idx8 = g << 3;
        int row = idx8 >> 9;                        // 0 .. 32*1025-1
        int col = idx8 & 511;
        int b    = (int)((unsigned)row / TP_);
        int trow = row - b * TP_;
        ushort8v o = {0, 0, 0, 0, 0, 0, 0, 0};
        if (trow > 0) {
            const float* src = &x[((size_t)b * T_ + (trow - 1)) * I_ + col];
            float4 v0 = *(const float4*)src;
            float4 v1 = *(const float4*)(src + 4);
            o[0] = f2bf(v0.x); o[1] = f2bf(v0.y); o[2] = f2bf(v0.z); o[3] = f2bf(v0.w);
            o[4] = f2bf(v1.x); o[5] = f2bf(v1.y); o[6] = f2bf(v1.z); o[7] = f2bf(v1.w);
        }
        *(ushort8v*)&Ab2[(size_t)idx8] = o;
    } else if (blockIdx.x < NB_BUILD + NB_PACK) {
        int cid = (blockIdx.x - NB_BUILD) * 256 + threadIdx.x;  // 0..131071
        int lane = cid & 63;
        int c    = (cid >> 6) & 3;
        int wn   = (cid >> 8) & 1;
        int ksub = (cid >> 9) & 31;
        int ni   = (cid >> 14) & 3;
        int gate = (cid >> 16) & 1;
        int n_col = ni * 128 + wn * 64 + c * 16 + (lane & 15);
        const float* G = gate ? Wz : Wf;
        ushort8v o;
        #pragma unroll
        for (int j = 0; j < 8; ++j) {
            int k   = ksub * 32 + (lane >> 4) * 8 + j;
            int tap = k >> 9;
            int i   = k & 511;
            o[j] = f2bf(G[n_col * (I_ * 2) + i * 2 + tap]);
        }
        *(ushort8v*)&Wq[(size_t)cid * 8] = o;
    } else {
        int g = (blockIdx.x - NB_BUILD - NB_PACK) * 256 + threadIdx.x; // 0..65535
        HpubZ[g] = make_uint4(0, 0, 0, 0);
        if (g < 128) tickets[g] = 0;
    }
}

// ---------------------------------------------------------------------------
// Fused dual-gate MFMA GEMM + full scan via decoupled lookback.
// EXACT revert to the round-9 kernel (session best: 85.2us, passed).
// Structure: blockIdx decode (4 ni-sharers same-XCD) + per-chain tickets;
// A via GLL ring-3 (8 KB slots); B in regs double-buffered one step ahead
// (L2-hot Wq); steady s_waitcnt vmcnt(2); one s_barrier per ksub;
// sched_barrier(0) pins load-issue above each MFMA cluster.
// Round-12's barrier-free variant (183us, MfmaUtil 15%) proved the GLL+
// lockstep staging was load-bearing: it coalesces A (direct per-lane loads
// are 16-way scattered) and GLL latency is covered by the ring depth.
// ---------------------------------------------------------------------------
__global__ __launch_bounds__(256, 2) void mfma_gemm_scan(
        const unsigned short* __restrict__ Ab2,  // [32][1025][512]
        const unsigned short* __restrict__ Wq,   // fragment-ordered, 2 MB
        const float* __restrict__ biasF,
        const float* __restrict__ biasZ,
        float* __restrict__ out,                 // [M_][512] fp32
        u64* __restrict__ Hpub,                  // [8][128][128]
        uint32_t* __restrict__ tickets) {        // 128 chain counters
    // A ring: slot j at smem + j*4096 shorts (8 KB each), 24 KB total.
    // Epilogue reuse: seg = float2[32][128] at [0,32KB); hinL at [32KB,48KB)
    __shared__ unsigned short smem[24576];       // 48 KB
    __shared__ uint32_t pos_s;

    const int tid = threadIdx.x;
    const int bid = blockIdx.x;
    const int x   = bid & 7;
    const int ni  = (bid >> 3) & 3;
    const int q   = bid >> 5;                    // 0..31
    const int b   = ((q & 3) << 3) | x;          // 0..31
    const int chain = ni * 32 + b;               // 0..127
    if (tid == 0) pos_s = atomicAdd(&tickets[chain], 1u);
    __syncthreads();
    const int pos = (int)pos_s;                  // 0..7 = start rank in chain
    const int h0  = ni * 128;
    const int browBase = b * TP_ + pos * 128;    // Ab2 row of tile, tap0

    const int lane = tid & 63;
    const int wave = tid >> 6;
    const int wm   = wave >> 1, wn = wave & 1;
    const int lm   = lane & 15, quad = lane >> 4;

    // A staging chunk ids (512 chunks/slot; wave covers 128: lane, lane+64)
    const int c0 = wave * 128 + lane;
    const int c1 = c0 + 64;
    const int r0 = c0 >> 2, q0 = (c0 & 3) ^ ((r0 >> 2) & 3);
    const int r1 = c1 >> 2, q1 = (c1 & 3) ^ ((r1 >> 2) & 3);

    const unsigned short* pA0 = Ab2 + (size_t)(browBase + r0) * 512 + q0 * 8;
    const unsigned short* pA1 = Ab2 + (size_t)(browBase + r1) * 512 + q1 * 8;

    // B direct global->VGPR (L2-hot): wave (wm,wn) consumes
    //   F frag c: Wq + ni*131072 + wn*2048 + ksub*4096 + c*512 + lane*8
    //   Z frag c: + 524288
    const unsigned short* pBF = Wq + ni * 131072 + wn * 2048 + lane * 8;

    int offA[4];
    #pragma unroll
    for (int r = 0; r < 4; ++r) {
        int ml = wm * 64 + r * 16 + lm;
        offA[r] = (4 * ml + (quad ^ ((ml >> 2) & 3))) * 8;
    }

    floatx4 accF[4][4] = {};
    floatx4 accZ[4][4] = {};
    bf16x8 bfA[4], bzA[4], bfB[4], bzB[4];

#define ISSUE_A(ksub, sA) do {                                          \
        const int aoff_ = (((ksub) >> 4) * 512) + (((ksub) & 15) * 32); \
        GLL(pA0 + aoff_, (sA) + wave * 1024);                           \
        GLL(pA1 + aoff_, (sA) + wave * 1024 + 512);                     \
    } while (0)

#define LOADB(ksub, BF, BZ) do {                                        \
        const unsigned short* pf_ = pBF + (ksub) * 4096;                \
        _Pragma("unroll")                                               \
        for (int c = 0; c < 4; ++c) {                                   \
            BF[c] = *(const bf16x8*)(pf_ + c * 512);                    \
            BZ[c] = *(const bf16x8*)(pf_ + 524288 + c * 512);           \
        }                                                               \
    } while (0)

#define MFMA32(AF, BF, BZ) do {                                         \
        __builtin_amdgcn_s_setprio(1);                                  \
        _Pragma("unroll")                                               \
        for (int r = 0; r < 4; ++r) {                                   \
            _Pragma("unroll")                                           \
            for (int c = 0; c < 4; ++c) {                               \
                accF[r][c] = __builtin_amdgcn_mfma_f32_16x16x32_bf16(   \
                                AF[r], BF[c], accF[r][c], 0, 0, 0);     \
                accZ[r][c] = __builtin_amdgcn_mfma_f32_16x16x32_bf16(   \
                                AF[r], BZ[c], accZ[r][c], 0, 0, 0);     \
            }                                                           \
        }                                                               \
        __builtin_amdgcn_s_setprio(0);                                  \
    } while (0)

#define RDA(slot, AF) do {                                              \
        _Pragma("unroll")                                               \
        for (int r = 0; r < 4; ++r)                                     \
            AF[r] = *(const bf16x8*)((slot) + offA[r]);                 \
    } while (0)

#define ROT() do { unsigned short* t_ = s0; s0 = s1; s1 = s2; s2 = t_; } while (0)

    unsigned short* s0 = smem;            // slot of ksub k   (compute)
    unsigned short* s1 = smem + 4096;     // ksub k+1 (in flight)
    unsigned short* s2 = smem + 8192;     // ksub k+2 (issue target)

    // prologue: A(0), A(1) staged; B(0) -> buffer A
    ISSUE_A(0, s0);
    ISSUE_A(1, s1);
    LOADB(0, bfA, bzA);

    // step 0 (compute bufA): drain prologue
    {
        asm volatile("s_waitcnt vmcnt(0)");
        __builtin_amdgcn_s_barrier();
        asm volatile("" ::: "memory");
        bf16x8 af_[4];
        RDA(s0, af_);
        LOADB(1, bfB, bzB);
        ISSUE_A(2, s2);
        __builtin_amdgcn_sched_barrier(0);
        MFMA32(af_, bfA, bzA);
        ROT();
    }
    // steps 1..28: pairs (odd computes bufB, even computes bufA)
    for (int p = 0; p < 14; ++p) {
        const int k1 = 2 * p + 1;
        {   // odd step k1: compute bufB, load B(k1+1)->bufA
            asm volatile("s_waitcnt vmcnt(2)");
            __builtin_amdgcn_s_barrier();
            asm volatile("" ::: "memory");
            bf16x8 af_[4];
            RDA(s0, af_);
            LOADB(k1 + 1, bfA, bzA);
            ISSUE_A(k1 + 2, s2);
            __builtin_amdgcn_sched_barrier(0);
            MFMA32(af_, bfB, bzB);
            ROT();
        }
        {   // even step k1+1: compute bufA, load B(k1+2)->bufB
            asm volatile("s_waitcnt vmcnt(2)");
            __builtin_amdgcn_s_barrier();
            asm volatile("" ::: "memory");
            bf16x8 af_[4];
            RDA(s0, af_);
            LOADB(k1 + 2, bfB, bzB);
            ISSUE_A(k1 + 3, s2);
            __builtin_amdgcn_sched_barrier(0);
            MFMA32(af_, bfA, bzA);
            ROT();
        }
    }
    // step 29 (odd): compute bufB, load B(30)->bufA, stage A(31)
    {
        asm volatile("s_waitcnt vmcnt(2)");
        __builtin_amdgcn_s_barrier();
        asm volatile("" ::: "memory");
        bf16x8 af_[4];
        RDA(s0, af_);
        LOADB(30, bfA, bzA);
        ISSUE_A(31, s2);
        __builtin_amdgcn_sched_barrier(0);
        MFMA32(af_, bfB, bzB);
        ROT();
    }
    // step 30 (even): compute bufA, load B(31)->bufB
    {
        asm volatile("s_waitcnt vmcnt(2)");
        __builtin_amdgcn_s_barrier();
        asm volatile("" ::: "memory");
        bf16x8 af_[4];
        RDA(s0, af_);
        LOADB(31, bfB, bzB);
        __builtin_amdgcn_sched_barrier(0);
        MFMA32(af_, bfA, bzA);
        ROT();
    }
    // step 31 (odd): drain, compute bufB
    {
        asm volatile("s_waitcnt vmcnt(0)");
        __builtin_amdgcn_s_barrier();
        asm volatile("" ::: "memory");
        bf16x8 af_[4];
        RDA(s0, af_);
        __builtin_amdgcn_sched_barrier(0);
        MFMA32(af_, bfB, bzB);
    }
#undef ISSUE_A
#undef LOADB
#undef MFMA32
#undef RDA
#undef ROT
    __syncthreads();   // all waves done with ring before smem is repurposed

    // ================= epilogue: sigmoid + segment affines =================
    float bfv[4], bzv[4];
    #pragma unroll
    for (int c = 0; c < 4; ++c) {
        int hc = h0 + wn * 64 + c * 16 + lm;
        bfv[c] = biasF[hc];
        bzv[c] = biasZ[hc];
    }

    float2* seg  = (float2*)smem;                // [32][128] 32 KB
    float*  hinL = (float*)&smem[16384];         // [32][128] 16 KB

    #pragma unroll
    for (int r = 0; r < 4; ++r) {
        const int sid = wm * 16 + r * 4 + quad;  // segment of 4 t's
        #pragma unroll
        for (int c = 0; c < 4; ++c) {
            float A = 1.f, C = 0.f;
            #pragma unroll
            for (int v = 0; v < 4; ++v) {
                float f = sigm(accF[r][c][v] + bfv[c]);
                float z = sigm(accZ[r][c][v] + bzv[c]);
                accF[r][c][v] = f;               // keep f
                accZ[r][c][v] = z;               // keep z
                A *= f;
                C = fmaf(f, C - z, z);
            }
            seg[sid * 128 + wn * 64 + c * 16 + lm] = make_float2(A, C);
        }
    }
    __syncthreads();

    // per-h block affine (threads 0..127), lookback, publish, local states
    if (tid < 128) {
        float At = 1.f, Ct = 0.f;
        #pragma unroll 8
        for (int s = 0; s < 32; ++s) {
            float2 sc = seg[s * 128 + tid];
            Ct = fmaf(sc.x, Ct, sc.y);
            At *= sc.x;
        }
        float Hin = 0.f;
        if (pos > 0) {
            u64* p = &Hpub[((size_t)(pos - 1) * 128 + chain) * 128 + tid];
            u64 v;
            while (((v = atomicAdd(p, 0ull)) >> 32) == 0ull)
                __builtin_amdgcn_s_sleep(2);
            Hin = __uint_as_float((uint32_t)v);
        }
        if (pos < 7) {
            float Hout = fmaf(At, Hin, Ct);
            u64 pv = 0x100000000ull | (u64)__float_as_uint(Hout);
            atomicExch(&Hpub[((size_t)pos * 128 + chain) * 128 + tid], pv);
        }
        // per-segment entry states
        float run = Hin;
        #pragma unroll 8
        for (int s = 0; s < 32; ++s) {
            hinL[s * 128 + tid] = run;
            float2 sc = seg[s * 128 + tid];
            run = fmaf(sc.x, run, sc.y);
        }
    }
    __syncthreads();

    // replay tile from registers, write output
    const int rowBase = b * T_ + pos * 128;
    #pragma unroll
    for (int r = 0; r < 4; ++r) {
        const int sid = wm * 16 + r * 4 + quad;
        #pragma unroll
        for (int c = 0; c < 4; ++c) {
            const int hc = h0 + wn * 64 + c * 16 + lm;
            float hs = hinL[sid * 128 + (hc - h0)];
            #pragma unroll
            for (int v = 0; v < 4; ++v) {
                float f = accF[r][c][v];
                float z = accZ[r][c][v];
                hs = fmaf(f, hs - z, z);
                const size_t row = (size_t)(rowBase + wm * 64 + r * 16 + quad * 4 + v);
                out[row * H_ + hc] = hs;
            }
        }
    }
}

// ---------------------------------------------------------------------------
extern "C" void kernel_launch(void* const* d_in, const int* in_sizes, int n_in,
                              void* d_out, int out_size, void* d_ws, size_t ws_size,
                              hipStream_t stream) {
    const float* x  = (const float*)d_in[0];
    const float* Wz = (const float*)d_in[2];
    const float* bz = (const float*)d_in[3];
    const float* Wf = (const float*)d_in[4];
    const float* bf = (const float*)d_in[5];
    float* out = (float*)d_out;

    char* ws = (char*)d_ws;
    unsigned short* Ab2  = (unsigned short*)(ws);                            // 33.6 MB
    unsigned short* Wq   = (unsigned short*)(ws + (size_t)34 * 1024 * 1024); // 2 MB
    u64*            Hpub = (u64*)(ws + (size_t)36 * 1024 * 1024);            // 1 MB
    uint32_t*       tkt  = (uint32_t*)(ws + (size_t)37 * 1024 * 1024);       // 512 B

    prep<<<NB_BUILD + NB_PACK + NB_ZERO, 256, 0, stream>>>(
        x, Wf, Wz, Ab2, Wq, (uint4*)Hpub, tkt);

    mfma_gemm_scan<<<1024, 256, 0, stream>>>(Ab2, Wq, bf, bz, out, Hpub, tkt);
}